// Round 20
// baseline (1928.873 us; speedup 1.0000x reference)
//
#include <hip/hip_runtime.h>
#include <hip/hip_bf16.h>
#include <cstdint>
#include <cstddef>

typedef __bf16 bf16_t;
typedef __attribute__((ext_vector_type(8))) __bf16 bf16x8;
typedef __attribute__((ext_vector_type(4))) __bf16 bf16x4;
typedef __attribute__((ext_vector_type(4))) float f32x4;

#define DEV __device__ __forceinline__

DEV void async16(const bf16_t* g, bf16_t* l) {
  __builtin_amdgcn_global_load_lds((const __attribute__((address_space(1))) void*)g,
                                   (__attribute__((address_space(3))) void*)l, 16, 0, 0);
}

DEV float fast_tanh(float x) {
  const float ex = __expf(2.f * x);
  return 1.f - 2.f / (ex + 1.f);
}

enum { EPI_RESID = 0, EPI_FFN1 = 1, EPI_QKV = 2, EPI_SCORE = 3, EPI_PV = 4, EPI_DELTAT = 5 };

// Split-bf16 GEMM, 64x128 tile (SCORE / PV): doubles grid to 512 blocks ->
// 2 blocks/CU (cross-block latency hiding, the r10/r16 mechanism).
// Same staging/dbuf/counted-vmcnt/XCD-swizzle skeleton as the proven gemm_k,
// M-dim resized: 4 waves each own 32 of the 128 N-cols; acc 4x2.
template<int EPI, bool TRANSB>
__global__ __launch_bounds__(256, 2)
void gemm64_k(const bf16_t* __restrict__ A, const bf16_t* __restrict__ A2,
              const bf16_t* __restrict__ B, const bf16_t* __restrict__ B2,
              void* __restrict__ outp, void* __restrict__ outp2,
              int Kd, int lda, int ldb, long aStride, long bStride)
{
  __shared__ bf16_t sA [2][2048];
  __shared__ bf16_t sA2[2][2048];
  __shared__ bf16_t sB [2][4096];
  __shared__ bf16_t sB2[2][4096];

  const int tid  = threadIdx.x;
  const int lane = tid & 63;
  const int wv   = tid >> 6;       // 0..3 (wave owns 32 N-cols)
  const int l15  = lane & 15;
  const int lg   = lane >> 4;

  // XCD-aware bijective remap
  unsigned gx = gridDim.x, gy = gridDim.y;
  unsigned nb = gx * gy * gridDim.z;
  unsigned fid = blockIdx.x + gx * (blockIdx.y + gy * blockIdx.z);
  if ((nb & 7u) == 0u) fid = (fid & 7u) * (nb >> 3) + (fid >> 3);
  const unsigned bxu = fid % gx;
  const unsigned rem = fid / gx;
  const unsigned byu = rem % gy;
  const unsigned bzu = rem / gy;
  const int m0 = byu * 64;
  const int n0 = bxu * 128;
  const int bz = bzu;

  const bf16_t *Ab, *Bb, *A2b, *B2b;
  if constexpr (EPI == EPI_SCORE) {
    const int h = bz & 7;
    const long ho = (long)(bz >> 3) * 512;   // split-K2 offset into head-dim 1024
    Ab  = A  + (long)h * aStride + ho;
    Bb  = B  + (long)h * bStride + ho;
    A2b = A2 + (long)h * aStride + ho;
    B2b = B2 + (long)h * bStride + ho;
  } else {
    Ab  = A  + (long)bz * aStride;
    Bb  = B  + (long)bz * bStride;
    A2b = A2 + (long)bz * aStride;
    B2b = B2 + (long)bz * bStride;
  }

  const int sRow = tid >> 2;        // 0..63
  const int sKo  = (tid & 3) * 8;   // 0,8,16,24
  const int tr = tid & 15;          // k row (TRANSB staging)
  const int tc = tid >> 4;          // n chunk of 8

  f32x4 acc[4][2];
#pragma unroll
  for (int i = 0; i < 4; i++)
#pragma unroll
    for (int j = 0; j < 2; j++) acc[i][j] = f32x4{0.f, 0.f, 0.f, 0.f};

  const int ns  = Kd >> 5;
  const int off = (int)(fid & (unsigned)(ns - 1));

  uint4 br0, br1, br2, br3;

  auto stageA = [&](int si, int b) {
    const int kt = ((si + off) & (ns - 1)) << 5;
    const bf16_t* ga  = Ab  + (long)(m0 + sRow) * lda + kt + sKo;
    const bf16_t* ga2 = A2b + (long)(m0 + sRow) * lda + kt + sKo;
    async16(ga,  &sA [b][tid * 8]);
    async16(ga2, &sA2[b][tid * 8]);
  };
  auto stageB = [&](int si, int b) {
    const int kt = ((si + off) & (ns - 1)) << 5;
    const bf16_t* gb  = Bb  + (long)(n0 + sRow) * ldb + kt + sKo;
    const bf16_t* gb2 = B2b + (long)(n0 + sRow) * ldb + kt + sKo;
    async16(gb,             &sB [b][tid * 8]);
    async16(gb + 64 * ldb,  &sB [b][2048 + tid * 8]);
    async16(gb2,            &sB2[b][tid * 8]);
    async16(gb2 + 64 * ldb, &sB2[b][2048 + tid * 8]);
  };
  auto loadBR = [&](int si) {
    const int kt = ((si + off) & (ns - 1)) << 5;
    const bf16_t* gb  = Bb  + (long)(kt + tr) * ldb + n0 + tc * 8;
    const bf16_t* gb2 = B2b + (long)(kt + tr) * ldb + n0 + tc * 8;
    br0 = *(const uint4*)gb;
    br1 = *(const uint4*)(gb + 16 * ldb);
    br2 = *(const uint4*)gb2;
    br3 = *(const uint4*)(gb2 + 16 * ldb);
  };

  stageA(0, 0);
  if constexpr (!TRANSB) stageB(0, 0); else loadBR(0);

  for (int si = 0; si < ns; si++) {
    const int cb = si & 1;
    if (si + 1 < ns) stageA(si + 1, cb ^ 1);
    if constexpr (TRANSB) {
      const bf16_t* e0 = (const bf16_t*)&br0;
      const bf16_t* e1 = (const bf16_t*)&br1;
      const bf16_t* e2 = (const bf16_t*)&br2;
      const bf16_t* e3 = (const bf16_t*)&br3;
#pragma unroll
      for (int j = 0; j < 8; j++) {
        sB [cb][(tc * 8 + j) * 32 + tr]      = e0[j];
        sB [cb][(tc * 8 + j) * 32 + tr + 16] = e1[j];
        sB2[cb][(tc * 8 + j) * 32 + tr]      = e2[j];
        sB2[cb][(tc * 8 + j) * 32 + tr + 16] = e3[j];
      }
      if (si + 1 < ns) loadBR(si + 1);
      if (si + 1 >= ns) asm volatile("s_waitcnt vmcnt(0)" ::: "memory");
    } else {
      if (si + 1 < ns) {
        stageB(si + 1, cb ^ 1);
        asm volatile("s_waitcnt vmcnt(6)" ::: "memory");  // stage(si) complete; si+1 (6 ops) in flight
      } else {
        asm volatile("s_waitcnt vmcnt(0)" ::: "memory");
      }
    }
    __syncthreads();

    bf16x8 af[4], af2[4], bfr[2], bf2[2];
#pragma unroll
    for (int i = 0; i < 4; i++) {
      const int ao = (i * 16 + l15) * 32 + lg * 8;
      af[i]  = *(const bf16x8*)&sA [cb][ao];
      af2[i] = *(const bf16x8*)&sA2[cb][ao];
    }
#pragma unroll
    for (int j = 0; j < 2; j++) {
      const int bo = (wv * 32 + j * 16 + l15) * 32 + lg * 8;
      bfr[j] = *(const bf16x8*)&sB [cb][bo];
      bf2[j] = *(const bf16x8*)&sB2[cb][bo];
    }
#pragma unroll
    for (int i = 0; i < 4; i++)
#pragma unroll
      for (int j = 0; j < 2; j++) {
        acc[i][j] = __builtin_amdgcn_mfma_f32_16x16x32_bf16(af[i],  bfr[j], acc[i][j], 0, 0, 0);
        acc[i][j] = __builtin_amdgcn_mfma_f32_16x16x32_bf16(af[i],  bf2[j], acc[i][j], 0, 0, 0);
        acc[i][j] = __builtin_amdgcn_mfma_f32_16x16x32_bf16(af2[i], bfr[j], acc[i][j], 0, 0, 0);
      }
    __syncthreads();
  }

  const int rg = lg * 4;
#pragma unroll
  for (int i = 0; i < 4; i++) {
    const int mb = m0 + i * 16 + rg;
#pragma unroll
    for (int j = 0; j < 2; j++) {
      const int n = n0 + wv * 32 + j * 16 + l15;
#pragma unroll
      for (int r = 0; r < 4; r++) {
        const int m = mb + r;
        const float v = acc[i][j][r];
        if constexpr (EPI == EPI_SCORE) {
          const int h = bz & 7, half = bz >> 3;
          float* dst = half ? (float*)outp2 : (float*)outp;
          dst[(long)h * 262144 + (long)m * 512 + n] = v * (1.f / 32.f);
        } else { // EPI_PV
          const int kb = n >> 5, dd = n & 31;
          const long oidx = (long)(m * 32 + kb) * 256 + bz * 32 + dd;
          const bf16_t hh = (bf16_t)v;
          ((bf16_t*)outp)[oidx]  = hh;
          ((bf16_t*)outp2)[oidx] = (bf16_t)(v - (float)hh);
        }
      }
    }
  }
}

// Activation x Weight split-bf16 GEMM (v4 structure, wave-private W) - r19 verified
template<int EPI>
__global__ __launch_bounds__(256, 2)
void awgemm_k(const bf16_t* __restrict__ Ah, const bf16_t* __restrict__ Al,
              const bf16_t* __restrict__ Wh, const bf16_t* __restrict__ Wl,
              const float* __restrict__ bias, void* __restrict__ outp, void* __restrict__ outp2)
{
  __shared__ bf16_t sAh[32 * 256], sAl[32 * 256];
  __shared__ bf16_t sW[4][4096];

  const int tid  = threadIdx.x;
  const int lane = tid & 63;
  const int wn   = tid >> 6;
  const int l15  = lane & 15;
  const int lg   = lane >> 4;
  const int n0   = blockIdx.x * 128;
  const int m0   = blockIdx.y * 32;
  const int soff = (blockIdx.y ^ blockIdx.x) & 7;

#pragma unroll
  for (int r = 0; r < 4; r++) {
    const int idx = r * 256 + tid;
    const int row = idx >> 5, cp = idx & 31;
    const int c = cp ^ (row & 31);
    async16(Ah + (long)(m0 + row) * 256 + c * 8, sAh + idx * 8);
    async16(Al + (long)(m0 + row) * 256 + c * 8, sAl + idx * 8);
  }
  asm volatile("s_waitcnt vmcnt(0)" ::: "memory");
  __syncthreads();

  bf16_t* myW = &sW[wn][0];
  const int wrow1 = lane >> 2;
  const int wsrc  = ((lane & 3) ^ ((lane >> 2) & 3)) * 8;
  const int rpc   = (lg ^ (l15 & 3)) * 8;

  auto stageW = [&](int sp, int b) {
#pragma unroll
    for (int q = 0; q < 2; q++) {
      const long r = n0 + wn * 32 + q * 16 + wrow1;
      async16(Wh + r * 256 + sp * 32 + wsrc, myW + b * 2048 + q * 512 + lane * 8);
      async16(Wl + r * 256 + sp * 32 + wsrc, myW + b * 2048 + 1024 + q * 512 + lane * 8);
    }
  };

  f32x4 acc[2][2];
#pragma unroll
  for (int i = 0; i < 2; i++)
#pragma unroll
    for (int j = 0; j < 2; j++) acc[i][j] = f32x4{0.f, 0.f, 0.f, 0.f};

  stageW(soff & 7, 0);
  for (int s = 0; s < 8; s++) {
    const int b = s & 1;
    const int sp = (s + soff) & 7;
    if (s < 7) {
      stageW((s + 1 + soff) & 7, b ^ 1);
      asm volatile("s_waitcnt vmcnt(4)" ::: "memory");
    } else {
      asm volatile("s_waitcnt vmcnt(0)" ::: "memory");
    }
    bf16x8 a_h[2], a_l[2], w_h[2], w_l[2];
#pragma unroll
    for (int i = 0; i < 2; i++) {
      const int arow = i * 16 + l15;
      const int ac = (sp * 4 + lg) ^ (arow & 31);
      a_h[i] = *(const bf16x8*)&sAh[arow * 256 + ac * 8];
      a_l[i] = *(const bf16x8*)&sAl[arow * 256 + ac * 8];
    }
#pragma unroll
    for (int j = 0; j < 2; j++) {
      const int r = j * 16 + l15;
      w_h[j] = *(const bf16x8*)&myW[b * 2048 + r * 32 + rpc];
      w_l[j] = *(const bf16x8*)&myW[b * 2048 + 1024 + r * 32 + rpc];
    }
#pragma unroll
    for (int i = 0; i < 2; i++)
#pragma unroll
      for (int j = 0; j < 2; j++) {
        acc[i][j] = __builtin_amdgcn_mfma_f32_16x16x32_bf16(a_h[i], w_h[j], acc[i][j], 0, 0, 0);
        acc[i][j] = __builtin_amdgcn_mfma_f32_16x16x32_bf16(a_h[i], w_l[j], acc[i][j], 0, 0, 0);
        acc[i][j] = __builtin_amdgcn_mfma_f32_16x16x32_bf16(a_l[i], w_h[j], acc[i][j], 0, 0, 0);
      }
  }

#pragma unroll
  for (int i = 0; i < 2; i++)
#pragma unroll
    for (int j = 0; j < 2; j++) {
      const int n = n0 + wn * 32 + j * 16 + l15;
#pragma unroll
      for (int rr = 0; rr < 4; rr++) {
        const int m = m0 + i * 16 + lg * 4 + rr;
        const float v = acc[i][j][rr];
        if constexpr (EPI == EPI_QKV) {
          const int s = m >> 5, kb = m & 31;
          const int proj = n >> 8, col = n & 255;
          const int h = col >> 5, dd = col & 31;
          const long oidx = (long)proj * 4194304 + (long)(h * 512 + s) * 1024 + kb * 32 + dd;
          const float t = v + bias[n * 32 + kb];
          const bf16_t hh = (bf16_t)t;
          ((bf16_t*)outp)[oidx]  = hh;
          ((bf16_t*)outp2)[oidx] = (bf16_t)(t - (float)hh);
        } else if constexpr (EPI == EPI_RESID) {
          ((float*)outp)[(long)m * 256 + n] += v + bias[n * 32 + (m & 31)];
        } else { // EPI_DELTAT
          const int b = m >> 14, t = (m >> 5) & 511, kb = m & 31;
          ((float*)outp)[(((long)(b * 256 + n) * 512 + t) * 32) + kb] = v + bias[n * 32 + kb];
        }
      }
    }
}

// Fused FFN v4 (r18/r19 verified)
__global__ __launch_bounds__(256, 2)
void ffn_k(const bf16_t* __restrict__ Ah, const bf16_t* __restrict__ Al,
           const bf16_t* __restrict__ W1h_, const bf16_t* __restrict__ W1l_,
           const bf16_t* __restrict__ W2h_, const bf16_t* __restrict__ W2l_,
           const float* __restrict__ b1, const float* __restrict__ b2,
           float* __restrict__ XT)
{
  __shared__ bf16_t sAh[32 * 256], sAl[32 * 256];
  __shared__ bf16_t sW[4][4096];
  __shared__ bf16_t sHh[32 * 128], sHl[32 * 128];

  const int tid  = threadIdx.x;
  const int lane = tid & 63;
  const int wn   = tid >> 6;
  const int l15  = lane & 15;
  const int lg   = lane >> 4;
  const int m0   = blockIdx.x * 32;
  const int coff = blockIdx.x & 7;
  const int soff = (blockIdx.x >> 3) & 7;
  const int toff = (blockIdx.x >> 3) & 3;

#pragma unroll
  for (int r = 0; r < 4; r++) {
    const int idx = r * 256 + tid;
    const int row = idx >> 5, cp = idx & 31;
    const int c = cp ^ (row & 31);
    async16(Ah + (long)(m0 + row) * 256 + c * 8, sAh + idx * 8);
    async16(Al + (long)(m0 + row) * 256 + c * 8, sAl + idx * 8);
  }
  asm volatile("s_waitcnt vmcnt(0)" ::: "memory");
  __syncthreads();

  bf16_t* myW = &sW[wn][0];
  const int wrow1 = lane >> 2;
  const int wsrc  = ((lane & 3) ^ ((lane >> 2) & 3)) * 8;
  const int rpc   = (lg ^ (l15 & 3)) * 8;

  f32x4 acc2[2][4];
#pragma unroll
  for (int i = 0; i < 2; i++)
#pragma unroll
    for (int j = 0; j < 4; j++) acc2[i][j] = f32x4{0.f, 0.f, 0.f, 0.f};

#pragma unroll 1
  for (int cc = 0; cc < 8; cc++) {
    const int ch = (cc + coff) & 7;
    const bf16_t* W1h = W1h_ + (long)(ch * 128) * 256;
    const bf16_t* W1l = W1l_ + (long)(ch * 128) * 256;

    auto stageW1 = [&](int sp, int b) {
#pragma unroll
      for (int q = 0; q < 2; q++) {
        const long r = wn * 32 + q * 16 + wrow1;
        async16(W1h + r * 256 + sp * 32 + wsrc, myW + b * 2048 + q * 512 + lane * 8);
        async16(W1l + r * 256 + sp * 32 + wsrc, myW + b * 2048 + 1024 + q * 512 + lane * 8);
      }
    };
    auto stageW2 = [&](int tp) {
#pragma unroll
      for (int q = 0; q < 4; q++) {
        const long r = wn * 64 + q * 16 + wrow1;
        async16(W2h_ + r * 1024 + ch * 128 + tp * 32 + wsrc, myW + q * 512 + lane * 8);
        async16(W2l_ + r * 1024 + ch * 128 + tp * 32 + wsrc, myW + 2048 + q * 512 + lane * 8);
      }
    };

    stageW1(soff & 7, 0);
    f32x4 acc1[2][2];
#pragma unroll
    for (int i = 0; i < 2; i++)
#pragma unroll
      for (int j = 0; j < 2; j++) acc1[i][j] = f32x4{0.f, 0.f, 0.f, 0.f};

    for (int s = 0; s < 8; s++) {
      const int b = s & 1;
      const int sp = (s + soff) & 7;
      if (s < 7) {
        stageW1((s + 1 + soff) & 7, b ^ 1);
        asm volatile("s_waitcnt vmcnt(4)" ::: "memory");
      } else {
        asm volatile("s_waitcnt vmcnt(0)" ::: "memory");
      }
      bf16x8 a_h[2], a_l[2], w_h[2], w_l[2];
#pragma unroll
      for (int i = 0; i < 2; i++) {
        const int arow = i * 16 + l15;
        const int ac = (sp * 4 + lg) ^ (arow & 31);
        a_h[i] = *(const bf16x8*)&sAh[arow * 256 + ac * 8];
        a_l[i] = *(const bf16x8*)&sAl[arow * 256 + ac * 8];
      }
#pragma unroll
      for (int j = 0; j < 2; j++) {
        const int r = j * 16 + l15;
        w_h[j] = *(const bf16x8*)&myW[b * 2048 + r * 32 + rpc];
        w_l[j] = *(const bf16x8*)&myW[b * 2048 + 1024 + r * 32 + rpc];
      }
#pragma unroll
      for (int i = 0; i < 2; i++)
#pragma unroll
        for (int j = 0; j < 2; j++) {
          acc1[i][j] = __builtin_amdgcn_mfma_f32_16x16x32_bf16(w_h[j], a_h[i], acc1[i][j], 0, 0, 0);
          acc1[i][j] = __builtin_amdgcn_mfma_f32_16x16x32_bf16(w_h[j], a_l[i], acc1[i][j], 0, 0, 0);
          acc1[i][j] = __builtin_amdgcn_mfma_f32_16x16x32_bf16(w_l[j], a_h[i], acc1[i][j], 0, 0, 0);
        }
    }

    asm volatile("s_waitcnt lgkmcnt(0)" ::: "memory");
    stageW2(toff & 3);

#pragma unroll
    for (int i = 0; i < 2; i++) {
      const int m = i * 16 + l15;
      const int kb = (m0 + m) & 31;
#pragma unroll
      for (int j = 0; j < 2; j++) {
        const int u = wn * 4 + j * 2 + (lg >> 1);
        const int pu = u ^ (m & 7);
        const int base = m * 128 + pu * 8 + (lg & 1) * 4;
        const int ncol = wn * 32 + j * 16 + lg * 4;
        bf16x4 h4, l4;
#pragma unroll
        for (int rr = 0; rr < 4; rr++) {
          const float t = fast_tanh(acc1[i][j][rr] + b1[(ch * 128 + ncol + rr) * 32 + kb]);
          const bf16_t hh = (bf16_t)t;
          h4[rr] = hh;
          l4[rr] = (bf16_t)(t - (float)hh);
        }
        *(bf16x4*)&sHh[base] = h4;
        *(bf16x4*)&sHl[base] = l4;
      }
    }
    __syncthreads();

    for (int t = 0; t < 4; t++) {
      const int tp = (t + toff) & 3;
      asm volatile("s_waitcnt vmcnt(0)" ::: "memory");
      bf16x8 h_h[2], h_l[2], v_h[4], v_l[4];
#pragma unroll
      for (int i = 0; i < 2; i++) {
        const int hrow = i * 16 + l15;
        const int pu = (tp * 4 + lg) ^ (hrow & 7);
        h_h[i] = *(const bf16x8*)&sHh[hrow * 128 + pu * 8];
        h_l[i] = *(const bf16x8*)&sHl[hrow * 128 + pu * 8];
      }
#pragma unroll
      for (int j = 0; j < 4; j++) {
        const int r2 = j * 16 + l15;
        v_h[j] = *(const bf16x8*)&myW[r2 * 32 + rpc];
        v_l[j] = *(const bf16x8*)&myW[2048 + r2 * 32 + rpc];
      }
      if (t < 3) {
        asm volatile("s_waitcnt lgkmcnt(0)" ::: "memory");
        stageW2((t + 1 + toff) & 3);
      }
#pragma unroll
      for (int i = 0; i < 2; i++)
#pragma unroll
        for (int j = 0; j < 4; j++) {
          acc2[i][j] = __builtin_amdgcn_mfma_f32_16x16x32_bf16(h_h[i], v_h[j], acc2[i][j], 0, 0, 0);
          acc2[i][j] = __builtin_amdgcn_mfma_f32_16x16x32_bf16(h_h[i], v_l[j], acc2[i][j], 0, 0, 0);
          acc2[i][j] = __builtin_amdgcn_mfma_f32_16x16x32_bf16(h_l[i], v_h[j], acc2[i][j], 0, 0, 0);
        }
    }
    __syncthreads();
  }

#pragma unroll
  for (int i = 0; i < 2; i++)
#pragma unroll
    for (int j = 0; j < 4; j++) {
      const int n2 = wn * 64 + j * 16 + l15;
#pragma unroll
      for (int rr = 0; rr < 4; rr++) {
        const int m = m0 + i * 16 + lg * 4 + rr;
        XT[(long)m * 256 + n2] += acc2[i][j][rr] + b2[n2 * 32 + (m & 31)];
      }
    }
}

// dst[b][c][r] = src[b][r][c], 32x32 tiles
__global__ __launch_bounds__(256)
void transpose_k(const float* __restrict__ src, float* __restrict__ dst, int R, int C)
{
  __shared__ float t[32][33];
  const long boff = (long)blockIdx.z * R * C;
  const int r0 = blockIdx.y * 32, c0 = blockIdx.x * 32;
  const int tx = threadIdx.x & 31, ty = threadIdx.x >> 5;
#pragma unroll
  for (int i = 0; i < 32; i += 8)
    t[ty + i][tx] = src[boff + (long)(r0 + ty + i) * C + c0 + tx];
  __syncthreads();
#pragma unroll
  for (int i = 0; i < 32; i += 8)
    dst[boff + (long)(c0 + ty + i) * R + r0 + tx] = t[tx][ty + i];
}

DEV void hilo4(const f32x4 t, bf16x4& h, bf16x4& l) {
#pragma unroll
  for (int j = 0; j < 4; j++) {
    const bf16_t hh = (bf16_t)t[j];
    h[j] = hh;
    l[j] = (bf16_t)(t[j] - (float)hh);
  }
}

// Fused normalize_cl41 + layernorm2d (unchanged)
template<int MODE>
__global__ __launch_bounds__(256)
void nl_k(const float* __restrict__ X, float* __restrict__ Xo,
          const float* __restrict__ wT, const float* __restrict__ bT,
          bf16_t* __restrict__ oh, bf16_t* __restrict__ ol)
{
  const int row = blockIdx.x * 4 + (threadIdx.x >> 6);
  const int l   = threadIdx.x & 63;
  const float4* Xr = (const float4*)X + (long)row * 2048 + l;
  f32x4 v[32];
#pragma unroll
  for (int kb = 0; kb < 32; kb++) {
    const float4 t = Xr[kb * 64];
    v[kb] = f32x4{t.x, t.y, t.z, t.w};
  }
  if constexpr (MODE & 1) {
    f32x4 ss = f32x4{1e-6f, 1e-6f, 1e-6f, 1e-6f};
#pragma unroll
    for (int kb = 0; kb < 32; kb++) ss += v[kb] * v[kb];
    const f32x4 rs = f32x4{rsqrtf(ss[0]), rsqrtf(ss[1]), rsqrtf(ss[2]), rsqrtf(ss[3])};
#pragma unroll
    for (int kb = 0; kb < 32; kb++) v[kb] *= rs;
    if constexpr (MODE & 2) {
      float4* Xw = (float4*)Xo + (long)row * 2048 + l;
#pragma unroll
      for (int kb = 0; kb < 32; kb++)
        Xw[kb * 64] = float4{v[kb][0], v[kb][1], v[kb][2], v[kb][3]};
    }
  }
  if constexpr (MODE & 4) {
    float s = 0.f, s2 = 0.f;
#pragma unroll
    for (int kb = 0; kb < 32; kb++) {
      s  += (v[kb][0] + v[kb][1]) + (v[kb][2] + v[kb][3]);
      s2 += (v[kb][0] * v[kb][0] + v[kb][1] * v[kb][1]) +
            (v[kb][2] * v[kb][2] + v[kb][3] * v[kb][3]);
    }
#pragma unroll
    for (int o = 32; o > 0; o >>= 1) { s += __shfl_xor(s, o); s2 += __shfl_xor(s2, o); }
    const float mean = s * (1.f / 8192.f);
    const float var  = s2 * (1.f / 8192.f) - mean * mean;
    const float rstd = rsqrtf(var + 1e-5f);
    const float4* w4 = (const float4*)wT + l;
    const float4* b4 = (const float4*)bT + l;
#pragma unroll
    for (int kb = 0; kb < 32; kb++) {
      const float4 ww = w4[kb * 64];
      const float4 bb = b4[kb * 64];
      f32x4 t;
      t[0] = (v[kb][0] - mean) * rstd * ww.x + bb.x;
      t[1] = (v[kb][1] - mean) * rstd * ww.y + bb.y;
      t[2] = (v[kb][2] - mean) * rstd * ww.z + bb.z;
      t[3] = (v[kb][3] - mean) * rstd * ww.w + bb.w;
      bf16x4 h4, l4;
      hilo4(t, h4, l4);
      const long oi = (long)row * 8192 + kb * 256 + l * 4;
      *(bf16x4*)&oh[oi] = h4;
      *(bf16x4*)&ol[oi] = l4;
    }
  }
  if constexpr (MODE & 8) {
#pragma unroll
    for (int kb = 0; kb < 32; kb++) {
      bf16x4 h4, l4;
      hilo4(v[kb], h4, l4);
      const long oi = (long)row * 8192 + kb * 256 + l * 4;
      *(bf16x4*)&oh[oi] = h4;
      *(bf16x4*)&ol[oi] = l4;
    }
  }
}

// softmax over rows of 512 (summing split-K2 halves), one wave per row; hi/lo bf16 out
__global__ __launch_bounds__(256)
void softmax_k(const float* __restrict__ SC, const float* __restrict__ SC2,
               bf16_t* __restrict__ Ph, bf16_t* __restrict__ Pl)
{
  const int row = blockIdx.x * 4 + (threadIdx.x >> 6);
  const int lane = threadIdx.x & 63;
  const float* s1 = SC  + (long)row * 512;
  const float* s2 = SC2 + (long)row * 512;
  float4 a = *(const float4*)&s1[lane * 4];
  float4 c = *(const float4*)&s1[256 + lane * 4];
  const float4 a2 = *(const float4*)&s2[lane * 4];
  const float4 c2 = *(const float4*)&s2[256 + lane * 4];
  a.x += a2.x; a.y += a2.y; a.z += a2.z; a.w += a2.w;
  c.x += c2.x; c.y += c2.y; c.z += c2.z; c.w += c2.w;
  float mx = fmaxf(fmaxf(fmaxf(a.x, a.y), fmaxf(a.z, a.w)),
                   fmaxf(fmaxf(c.x, c.y), fmaxf(c.z, c.w)));
#pragma unroll
  for (int o = 32; o > 0; o >>= 1) mx = fmaxf(mx, __shfl_xor(mx, o));
  float e[8] = {expf(a.x - mx), expf(a.y - mx), expf(a.z - mx), expf(a.w - mx),
                expf(c.x - mx), expf(c.y - mx), expf(c.z - mx), expf(c.w - mx)};
  float sum = ((e[0] + e[1]) + (e[2] + e[3])) + ((e[4] + e[5]) + (e[6] + e[7]));
#pragma unroll
  for (int o = 32; o > 0; o >>= 1) sum += __shfl_xor(sum, o);
  const float inv = 1.f / sum;
  bf16x4 h0, h1, l0, l1;
#pragma unroll
  for (int j = 0; j < 4; j++) {
    const float p0 = e[j] * inv, p1 = e[4 + j] * inv;
    h0[j] = (bf16_t)p0; l0[j] = (bf16_t)(p0 - (float)h0[j]);
    h1[j] = (bf16_t)p1; l1[j] = (bf16_t)(p1 - (float)h1[j]);
  }
  *(bf16x4*)&Ph[(long)row * 512 + lane * 4] = h0;
  *(bf16x4*)&Ph[(long)row * 512 + 256 + lane * 4] = h1;
  *(bf16x4*)&Pl[(long)row * 512 + lane * 4] = l0;
  *(bf16x4*)&Pl[(long)row * 512 + 256 + lane * 4] = l1;
}

// compile-time Cayley sign for Cl(4,1): gp(e_i, e_j) = sign * e_{i^j}
constexpr float gpsign(int i, int j) {
  int cnt = 0;
  for (int s = 1; s < 5; s++) cnt += __builtin_popcount((i >> s) & j);
  float sgn = (cnt & 1) ? -1.f : 1.f;
  if ((i & j) & 16) sgn = -sgn;   // metric e4^2 = -1
  return sgn;
}

// per-thread full geometric product, fully unrolled, constant signs (no shuffles)
DEV void gp32(const float* __restrict__ a, const float* __restrict__ b, float* __restrict__ o) {
#pragma unroll
  for (int k = 0; k < 32; k++) {
    float s0 = 0.f, s1 = 0.f;
#pragma unroll
    for (int i = 0; i < 32; i += 2) {
      s0 = fmaf(gpsign(i, i ^ k) * a[i], b[i ^ k], s0);
      s1 = fmaf(gpsign(i + 1, (i + 1) ^ k) * a[i + 1], b[(i + 1) ^ k], s1);
    }
    o[k] = s0 + s1;
  }
}

// Tree-structured rotor product: psi = normalize(r_511 o ... o r_0).
__global__ __launch_bounds__(256)
void gptree_k(const float* __restrict__ dT, float* __restrict__ psiO)
{
  __shared__ float bufA[256 * 33];
  __shared__ float bufB[128 * 33];
  const int chain = blockIdx.x;
  const int t = threadIdx.x;
  const float* src = dT + (long)chain * (512 * 32);
  {
    float v[64];
    const float4* g = (const float4*)(src + t * 64);
#pragma unroll
    for (int i = 0; i < 16; i++) *(float4*)&v[i * 4] = g[i];
    float o[32];
    gp32(v + 32, v, o);               // left = later timestep
    float ss = 1e-6f;
#pragma unroll
    for (int k = 0; k < 32; k++) ss = fmaf(o[k], o[k], ss);
    const float rs = rsqrtf(ss);
#pragma unroll
    for (int k = 0; k < 32; k++) bufA[t * 33 + k] = o[k] * rs;
  }
  __syncthreads();
  int cur = 0;
#pragma unroll 1
  for (int P = 128; P >= 1; P >>= 1) {
    const float* in = cur ? bufB : bufA;
    float* ob = cur ? bufA : bufB;
    if (t < P) {
      float a[32], b[32], o[32];
#pragma unroll
      for (int c = 0; c < 32; c++) { b[c] = in[t * 66 + c]; a[c] = in[t * 66 + 33 + c]; }
      gp32(a, b, o);
      float ss = 1e-6f;
#pragma unroll
      for (int k = 0; k < 32; k++) ss = fmaf(o[k], o[k], ss);
      const float rs = rsqrtf(ss);
#pragma unroll
      for (int k = 0; k < 32; k++) ob[t * 33 + k] = o[k] * rs;
    }
    cur ^= 1;
    __syncthreads();
  }
  if (t < 32) psiO[(long)chain * 32 + t] = (cur ? bufB : bufA)[t];
}

// logits[b, c] = psi[b,:] . wc[c,:] + bc[c]; one block per class
__global__ __launch_bounds__(256)
void cls_k(const float* __restrict__ psi, const float* __restrict__ wcw,
           const float* __restrict__ bc, float* __restrict__ out)
{
  const int c = blockIdx.x;
  const int tid = threadIdx.x;
  float a0 = 0.f, a1 = 0.f, a2 = 0.f, a3 = 0.f;
  for (int i = tid * 4; i < 8192; i += 1024) {
    const float4 w  = *(const float4*)&wcw[(long)c * 8192 + i];
    const float4 p0 = *(const float4*)&psi[i];
    const float4 p1 = *(const float4*)&psi[8192 + i];
    const float4 p2 = *(const float4*)&psi[16384 + i];
    const float4 p3 = *(const float4*)&psi[24576 + i];
    a0 += w.x * p0.x + w.y * p0.y + w.z * p0.z + w.w * p0.w;
    a1 += w.x * p1.x + w.y * p1.y + w.z * p1.z + w.w * p1.w;
    a2 += w.x * p2.x + w.y * p2.y + w.z * p2.z + w.w * p2.w;
    a3 += w.x * p3.x + w.y * p3.y + w.z * p3.z + w.w * p3.w;
  }
#pragma unroll
  for (int o = 32; o > 0; o >>= 1) {
    a0 += __shfl_down(a0, o); a1 += __shfl_down(a1, o);
    a2 += __shfl_down(a2, o); a3 += __shfl_down(a3, o);
  }
  __shared__ float red[4][4];
  const int wv = tid >> 6;
  if ((tid & 63) == 0) { red[wv][0] = a0; red[wv][1] = a1; red[wv][2] = a2; red[wv][3] = a3; }
  __syncthreads();
  if (tid < 4) {
    const float r = red[0][tid] + red[1][tid] + red[2][tid] + red[3][tid] + bc[c];
    out[(long)tid * 1000 + c] = r;
  }
}

__global__ void split_k(const float* __restrict__ in, bf16_t* __restrict__ h,
                        bf16_t* __restrict__ l, int n)
{
  const int i = blockIdx.x * 256 + threadIdx.x;
  if (i < n) {
    const float v = in[i];
    const bf16_t hh = (bf16_t)v;
    h[i] = hh;
    l[i] = (bf16_t)(v - (float)hh);
  }
}

__global__ void cpy_k(const float* __restrict__ in, float* __restrict__ o, int n)
{
  const int i = blockIdx.x * 256 + threadIdx.x;
  if (i < n) o[i] = in[i];
}

extern "C" void kernel_launch(void* const* d_in, const int* in_sizes, int n_in,
                              void* d_out, int out_size, void* d_ws, size_t ws_size,
                              hipStream_t stream)
{
  const float* x    = (const float*)d_in[0];
  const float* ln1w = (const float*)d_in[1];
  const float* ln1b = (const float*)d_in[2];
  const float* wq   = (const float*)d_in[3];
  const float* bq   = (const float*)d_in[4];
  const float* wk   = (const float*)d_in[5];
  const float* bk   = (const float*)d_in[6];
  const float* wvv  = (const float*)d_in[7];
  const float* bv   = (const float*)d_in[8];
  const float* wo   = (const float*)d_in[9];
  const float* bo   = (const float*)d_in[10];
  const float* ln2w = (const float*)d_in[11];
  const float* ln2b = (const float*)d_in[12];
  const float* w1   = (const float*)d_in[13];
  const float* b1   = (const float*)d_in[14];
  const float* w2   = (const float*)d_in[15];
  const float* b2   = (const float*)d_in[16];
  const float* wr   = (const float*)d_in[17];
  const float* br   = (const float*)d_in[18];
  const float* wcw  = (const float*)d_in[19];
  const float* bc   = (const float*)d_in[20];
  float* out = (float*)d_out;

  char* ws = (char*)d_ws;
  const size_t MB = 1ull << 20;
  const size_t KB = 1024;
  float*  XT   = (float*)(ws + 0);
  bf16_t* HBh  = (bf16_t*)(ws + 64 * MB);
  bf16_t* HBl  = (bf16_t*)(ws + 96 * MB);
  bf16_t* QKVh = (bf16_t*)(ws + 128 * MB);
  bf16_t* QKVl = (bf16_t*)(ws + 152 * MB);
  float*  SCb  = (float*)(ws + 176 * MB);
  float*  SC2b = (float*)(ws + 184 * MB);
  bf16_t* Ph   = QKVh;
  bf16_t* Pl   = QKVl;
  bf16_t* OBh  = QKVh + 4194304;
  bf16_t* OBl  = QKVl + 4194304;
  bf16_t* Vh   = QKVh + 8388608;
  bf16_t* Vl   = QKVl + 8388608;
  bf16_t* XHI = (bf16_t*)(ws + 64 * MB), *XLO = (bf16_t*)(ws + 96 * MB);
  float*  DELTAT = (float*)(ws + 128 * MB);
  float*  PSI  = (float*)(ws + 192 * MB);
  char*   W    = ws + 193 * MB;
  bf16_t* WQKVh = (bf16_t*)(W);
  bf16_t* WQKVl = (bf16_t*)(W + 1 * MB);
  bf16_t* W1h = (bf16_t*)(W + 2 * MB);   bf16_t* W1l = (bf16_t*)(W + 3 * MB);
  bf16_t* W2h = (bf16_t*)(W + 4 * MB);   bf16_t* W2l = (bf16_t*)(W + 5 * MB);
  bf16_t* WOh = (bf16_t*)(W + 6 * MB);   bf16_t* WOl = (bf16_t*)(W + 6 * MB + 256 * KB);
  bf16_t* WRh = (bf16_t*)(W + 6 * MB + 512 * KB);
  bf16_t* WRl = (bf16_t*)(W + 6 * MB + 640 * KB);
  float*  BQKV = (float*)(W + 6 * MB + 768 * KB);
  float*  LNT  = (float*)(W + 6 * MB + 960 * KB);
  float* LN1WT = LNT, *LN1BT = LNT + 16384, *LN2WT = LNT + 32768, *LN2BT = LNT + 49152;

  for (int l = 0; l < 2; l++) {
    split_k<<<256, 256, 0, stream>>>(wq + l * 65536, WQKVh + l * 196608, WQKVl + l * 196608, 65536);
    split_k<<<256, 256, 0, stream>>>(wk + l * 65536, WQKVh + l * 196608 + 65536, WQKVl + l * 196608 + 65536, 65536);
    split_k<<<256, 256, 0, stream>>>(wvv + l * 65536, WQKVh + l * 196608 + 131072, WQKVl + l * 196608 + 131072, 65536);
    cpy_k<<<32, 256, 0, stream>>>(bq + l * 8192, BQKV + l * 24576, 8192);
    cpy_k<<<32, 256, 0, stream>>>(bk + l * 8192, BQKV + l * 24576 + 8192, 8192);
    cpy_k<<<32, 256, 0, stream>>>(bv + l * 8192, BQKV + l * 24576 + 16384, 8192);
  }
  split_k<<<512, 256, 0, stream>>>(wo, WOh, WOl, 131072);
  split_k<<<2048, 256, 0, stream>>>(w1, W1h, W1l, 524288);
  split_k<<<2048, 256, 0, stream>>>(w2, W2h, W2l, 524288);
  split_k<<<256, 256, 0, stream>>>(wr, WRh, WRl, 65536);
  transpose_k<<<dim3(1, 8, 2), 256, 0, stream>>>(ln1w, LN1WT, 256, 32);
  transpose_k<<<dim3(1, 8, 2), 256, 0, stream>>>(ln1b, LN1BT, 256, 32);
  transpose_k<<<dim3(1, 8, 2), 256, 0, stream>>>(ln2w, LN2WT, 256, 32);
  transpose_k<<<dim3(1, 8, 2), 256, 0, stream>>>(ln2b, LN2BT, 256, 32);

  transpose_k<<<dim3(1, 8, 2048), 256, 0, stream>>>(x, XT, 256, 32);

  for (int l = 0; l < 2; l++) {
    if (l == 0)
      nl_k<4><<<512, 256, 0, stream>>>(XT, nullptr, LN1WT, LN1BT, HBh, HBl);
    for (int b = 0; b < 4; b++) {
      const long ao = (long)b * 16384 * 256;
      awgemm_k<EPI_QKV><<<dim3(6, 512), 256, 0, stream>>>(
          HBh + ao, HBl + ao, WQKVh + l * 196608, WQKVl + l * 196608,
          BQKV + l * 24576, QKVh, QKVl);
      gemm64_k<EPI_SCORE, false><<<dim3(4, 8, 16), 256, 0, stream>>>(
          QKVh, QKVl, QKVh + 4194304, QKVl + 4194304,
          SCb, SC2b, 512, 1024, 1024, 512 * 1024, 512 * 1024);
      softmax_k<<<1024, 256, 0, stream>>>(SCb, SC2b, Ph, Pl);
      gemm64_k<EPI_PV, true><<<dim3(8, 8, 8), 256, 0, stream>>>(
          Ph, Pl, Vh, Vl, OBh, OBl, 512, 512, 1024, 512 * 512, 512 * 1024);
      awgemm_k<EPI_RESID><<<dim3(2, 512), 256, 0, stream>>>(
          OBh, OBl, WOh + l * 65536, WOl + l * 65536,
          bo + l * 8192, (float*)XT + ao, nullptr);
    }
    nl_k<1 | 2 | 4><<<512, 256, 0, stream>>>(XT, XT, LN2WT + l * 8192, LN2BT + l * 8192, HBh, HBl);
    ffn_k<<<2048, 256, 0, stream>>>(HBh, HBl,
                                    W1h + l * 262144, W1l + l * 262144,
                                    W2h + l * 262144, W2l + l * 262144,
                                    b1 + l * 32768, b2 + l * 8192, XT);
    if (l == 0) {
      nl_k<1 | 2 | 4><<<512, 256, 0, stream>>>(XT, XT, LN1WT + 8192, LN1BT + 8192, HBh, HBl);
    } else {
      nl_k<1 | 8><<<512, 256, 0, stream>>>(XT, nullptr, nullptr, nullptr, XHI, XLO);
    }
  }

  awgemm_k<EPI_DELTAT><<<dim3(2, 2048), 256, 0, stream>>>(
      XHI, XLO, WRh, WRl, br, DELTAT, nullptr);
  gptree_k<<<1024, 256, 0, stream>>>(DELTAT, PSI);
  cls_k<<<1000, 256, 0, stream>>>(PSI, wcw, bc, out);
}

// Round 21
// 1877.952 us; speedup vs baseline: 1.0271x; 1.0271x over previous
//
#include <hip/hip_runtime.h>
#include <hip/hip_bf16.h>
#include <cstdint>
#include <cstddef>

typedef __bf16 bf16_t;
typedef __attribute__((ext_vector_type(8))) __bf16 bf16x8;
typedef __attribute__((ext_vector_type(4))) __bf16 bf16x4;
typedef __attribute__((ext_vector_type(4))) float f32x4;

#define DEV __device__ __forceinline__

DEV void async16(const bf16_t* g, bf16_t* l) {
  __builtin_amdgcn_global_load_lds((const __attribute__((address_space(1))) void*)g,
                                   (__attribute__((address_space(3))) void*)l, 16, 0, 0);
}

DEV float fast_tanh(float x) {
  const float ex = __expf(2.f * x);
  return 1.f - 2.f / (ex + 1.f);
}

enum { EPI_RESID = 0, EPI_FFN1 = 1, EPI_QKV = 2, EPI_SCORE = 3, EPI_PV = 4, EPI_DELTAT = 5 };

// Split-bf16 GEMM: C = (Ah+Al)*(Bh+Bl)^T ~= Ah*Bh + Ah*Bl + Al*Bh  (fp32-grade)
// NT layout; TRANSB: B is KxN row-major, transposed into LDS via regs.
// 128x128 tile, BK=32, 4 waves. Double-buffered LDS + counted vmcnt.
// XCD-bijective swizzle + per-block K-phase rotation.  (r18-verified)
template<int EPI, bool TRANSB>
__global__ __launch_bounds__(256, 2)
void gemm_k(const bf16_t* __restrict__ A, const bf16_t* __restrict__ A2,
            const bf16_t* __restrict__ B, const bf16_t* __restrict__ B2,
            const float* __restrict__ bias, void* __restrict__ outp, void* __restrict__ outp2,
            int Kd, int lda, int ldb, long aStride, long bStride)
{
  __shared__ bf16_t sA [2][4096];
  __shared__ bf16_t sB [2][4096];
  __shared__ bf16_t sA2[2][4096];
  __shared__ bf16_t sB2[2][4096];

  const int tid  = threadIdx.x;
  const int lane = tid & 63;
  const int wv   = tid >> 6;
  const int wr   = wv >> 1, wc = wv & 1;

  unsigned gx = gridDim.x, gy = gridDim.y;
  unsigned nb = gx * gy * gridDim.z;
  unsigned fid = blockIdx.x + gx * (blockIdx.y + gy * blockIdx.z);
  if ((nb & 7u) == 0u) fid = (fid & 7u) * (nb >> 3) + (fid >> 3);
  const unsigned bxu = fid % gx;
  const unsigned rem = fid / gx;
  const unsigned byu = rem % gy;
  const unsigned bzu = rem / gy;
  const int m0 = byu * 128;
  const int n0 = bxu * 128;
  const int bz = bzu;

  const bf16_t *Ab, *Bb, *A2b, *B2b;
  if constexpr (EPI == EPI_SCORE) {
    const int h = bz & 7;
    const long ho = (long)(bz >> 3) * 512;   // split-K2 offset into head-dim 1024
    Ab  = A  + (long)h * aStride + ho;
    Bb  = B  + (long)h * bStride + ho;
    A2b = A2 + (long)h * aStride + ho;
    B2b = B2 + (long)h * bStride + ho;
  } else {
    Ab  = A  + (long)bz * aStride;
    Bb  = B  + (long)bz * bStride;
    A2b = A2 + (long)bz * aStride;
    B2b = B2 + (long)bz * bStride;
  }

  const int sRow = tid >> 2;        // 0..63
  const int sKo  = (tid & 3) * 8;   // 0,8,16,24
  const int tr = tid & 15;          // k row (TRANSB staging)
  const int tc = tid >> 4;          // n chunk of 8

  f32x4 acc[4][4];
#pragma unroll
  for (int i = 0; i < 4; i++)
#pragma unroll
    for (int j = 0; j < 4; j++) acc[i][j] = f32x4{0.f, 0.f, 0.f, 0.f};

  const int ns  = Kd >> 5;
  const int off = (int)(fid & (unsigned)(ns - 1));

  uint4 br0, br1, br2, br3;

  auto stageA = [&](int si, int b) {
    const int kt = ((si + off) & (ns - 1)) << 5;
    const bf16_t* ga  = Ab  + (long)(m0 + sRow) * lda + kt + sKo;
    const bf16_t* ga2 = A2b + (long)(m0 + sRow) * lda + kt + sKo;
    async16(ga,             &sA [b][tid * 8]);
    async16(ga + 64 * lda,  &sA [b][2048 + tid * 8]);
    async16(ga2,            &sA2[b][tid * 8]);
    async16(ga2 + 64 * lda, &sA2[b][2048 + tid * 8]);
  };
  auto stageB = [&](int si, int b) {
    const int kt = ((si + off) & (ns - 1)) << 5;
    const bf16_t* gb  = Bb  + (long)(n0 + sRow) * ldb + kt + sKo;
    const bf16_t* gb2 = B2b + (long)(n0 + sRow) * ldb + kt + sKo;
    async16(gb,             &sB [b][tid * 8]);
    async16(gb + 64 * ldb,  &sB [b][2048 + tid * 8]);
    async16(gb2,            &sB2[b][tid * 8]);
    async16(gb2 + 64 * ldb, &sB2[b][2048 + tid * 8]);
  };
  auto loadBR = [&](int si) {
    const int kt = ((si + off) & (ns - 1)) << 5;
    const bf16_t* gb  = Bb  + (long)(kt + tr) * ldb + n0 + tc * 8;
    const bf16_t* gb2 = B2b + (long)(kt + tr) * ldb + n0 + tc * 8;
    br0 = *(const uint4*)gb;
    br1 = *(const uint4*)(gb + 16 * ldb);
    br2 = *(const uint4*)gb2;
    br3 = *(const uint4*)(gb2 + 16 * ldb);
  };

  stageA(0, 0);
  if constexpr (!TRANSB) stageB(0, 0); else loadBR(0);

  for (int si = 0; si < ns; si++) {
    const int cb = si & 1;
    if (si + 1 < ns) stageA(si + 1, cb ^ 1);
    if constexpr (TRANSB) {
      const bf16_t* e0 = (const bf16_t*)&br0;
      const bf16_t* e1 = (const bf16_t*)&br1;
      const bf16_t* e2 = (const bf16_t*)&br2;
      const bf16_t* e3 = (const bf16_t*)&br3;
#pragma unroll
      for (int j = 0; j < 8; j++) {
        sB [cb][(tc * 8 + j) * 32 + tr]      = e0[j];
        sB [cb][(tc * 8 + j) * 32 + tr + 16] = e1[j];
        sB2[cb][(tc * 8 + j) * 32 + tr]      = e2[j];
        sB2[cb][(tc * 8 + j) * 32 + tr + 16] = e3[j];
      }
      if (si + 1 < ns) loadBR(si + 1);
      if (si + 1 >= ns) asm volatile("s_waitcnt vmcnt(0)" ::: "memory");
    } else {
      if (si + 1 < ns) {
        stageB(si + 1, cb ^ 1);
        asm volatile("s_waitcnt vmcnt(8)" ::: "memory");
      } else {
        asm volatile("s_waitcnt vmcnt(0)" ::: "memory");
      }
    }
    __syncthreads();

    bf16x8 af[4], bfr[4], af2[4], bf2[4];
#pragma unroll
    for (int i = 0; i < 4; i++) {
      const int ao = (wr * 64 + i * 16 + (lane & 15)) * 32 + (lane >> 4) * 8;
      const int bo = (wc * 64 + i * 16 + (lane & 15)) * 32 + (lane >> 4) * 8;
      af[i]  = *(const bf16x8*)&sA [cb][ao];
      af2[i] = *(const bf16x8*)&sA2[cb][ao];
      bfr[i] = *(const bf16x8*)&sB [cb][bo];
      bf2[i] = *(const bf16x8*)&sB2[cb][bo];
    }
#pragma unroll
    for (int i = 0; i < 4; i++)
#pragma unroll
      for (int j = 0; j < 4; j++) {
        acc[i][j] = __builtin_amdgcn_mfma_f32_16x16x32_bf16(af[i],  bfr[j], acc[i][j], 0, 0, 0);
        acc[i][j] = __builtin_amdgcn_mfma_f32_16x16x32_bf16(af[i],  bf2[j], acc[i][j], 0, 0, 0);
        acc[i][j] = __builtin_amdgcn_mfma_f32_16x16x32_bf16(af2[i], bfr[j], acc[i][j], 0, 0, 0);
      }
    __syncthreads();
  }

  const int cn = lane & 15;
  const int rg = (lane >> 4) * 4;
#pragma unroll
  for (int i = 0; i < 4; i++) {
    const int mb = m0 + wr * 64 + i * 16 + rg;
#pragma unroll
    for (int j = 0; j < 4; j++) {
      const int n = n0 + wc * 64 + j * 16 + cn;
#pragma unroll
      for (int r = 0; r < 4; r++) {
        const int m = mb + r;
        const float v = acc[i][j][r];
        if constexpr (EPI == EPI_RESID) {
          const float bb = bias ? bias[n * 32 + (m & 31)] : 0.f;
          ((float*)outp)[(long)m * 256 + n] += v + bb;
        } else if constexpr (EPI == EPI_QKV) {
          const int s = m >> 5, kb = m & 31;
          const int proj = n >> 8, col = n & 255;
          const int h = col >> 5, dd = col & 31;
          const long oidx = (long)proj * 4194304 + (long)(h * 512 + s) * 1024 + kb * 32 + dd;
          const float t = v + bias[n * 32 + kb];
          const bf16_t hh = (bf16_t)t;
          ((bf16_t*)outp)[oidx]  = hh;
          ((bf16_t*)outp2)[oidx] = (bf16_t)(t - (float)hh);
        } else if constexpr (EPI == EPI_SCORE) {
          const int h = bz & 7, half = bz >> 3;
          float* dst = half ? (float*)outp2 : (float*)outp;
          dst[(long)h * 262144 + (long)m * 512 + n] = v * (1.f / 32.f);
        } else if constexpr (EPI == EPI_PV) {
          const int kb = n >> 5, dd = n & 31;
          const long oidx = (long)(m * 32 + kb) * 256 + bz * 32 + dd;
          const bf16_t hh = (bf16_t)v;
          ((bf16_t*)outp)[oidx]  = hh;
          ((bf16_t*)outp2)[oidx] = (bf16_t)(v - (float)hh);
        } else { // EPI_DELTAT: m=(b,t,kb), n=d -> out[(b,d,t,kb)]
          const int b = m >> 14, t = (m >> 5) & 511, kb = m & 31;
          ((float*)outp)[(((long)(b * 256 + n) * 512 + t) * 32) + kb] = v + bias[n * 32 + kb];
        }
      }
    }
  }
}

// Fused FFN v4 (r18-verified): XT += tanh(LN2x @ W1^T + b1) @ W2^T + b2.
// Wave-private W staging via global_load_lds, zero barriers in k-loops,
// full 3-MFMA split (weight lo-terms REQUIRED per r17). LDS 80KB, 2 blk/CU.
__global__ __launch_bounds__(256, 2)
void ffn_k(const bf16_t* __restrict__ Ah, const bf16_t* __restrict__ Al,
           const bf16_t* __restrict__ W1h_, const bf16_t* __restrict__ W1l_,
           const bf16_t* __restrict__ W2h_, const bf16_t* __restrict__ W2l_,
           const float* __restrict__ b1, const float* __restrict__ b2,
           float* __restrict__ XT)
{
  __shared__ bf16_t sAh[32 * 256], sAl[32 * 256];
  __shared__ bf16_t sW[4][4096];
  __shared__ bf16_t sHh[32 * 128], sHl[32 * 128];

  const int tid  = threadIdx.x;
  const int lane = tid & 63;
  const int wn   = tid >> 6;
  const int l15  = lane & 15;
  const int lg   = lane >> 4;
  const int m0   = blockIdx.x * 32;
  const int coff = blockIdx.x & 7;
  const int soff = (blockIdx.x >> 3) & 7;
  const int toff = (blockIdx.x >> 3) & 3;

#pragma unroll
  for (int r = 0; r < 4; r++) {
    const int idx = r * 256 + tid;
    const int row = idx >> 5, cp = idx & 31;
    const int c = cp ^ (row & 31);
    async16(Ah + (long)(m0 + row) * 256 + c * 8, sAh + idx * 8);
    async16(Al + (long)(m0 + row) * 256 + c * 8, sAl + idx * 8);
  }
  asm volatile("s_waitcnt vmcnt(0)" ::: "memory");
  __syncthreads();

  bf16_t* myW = &sW[wn][0];
  const int wrow1 = lane >> 2;
  const int wsrc  = ((lane & 3) ^ ((lane >> 2) & 3)) * 8;
  const int rpc   = (lg ^ (l15 & 3)) * 8;

  f32x4 acc2[2][4];
#pragma unroll
  for (int i = 0; i < 2; i++)
#pragma unroll
    for (int j = 0; j < 4; j++) acc2[i][j] = f32x4{0.f, 0.f, 0.f, 0.f};

#pragma unroll 1
  for (int cc = 0; cc < 8; cc++) {
    const int ch = (cc + coff) & 7;
    const bf16_t* W1h = W1h_ + (long)(ch * 128) * 256;
    const bf16_t* W1l = W1l_ + (long)(ch * 128) * 256;

    auto stageW1 = [&](int sp, int b) {
#pragma unroll
      for (int q = 0; q < 2; q++) {
        const long r = wn * 32 + q * 16 + wrow1;
        async16(W1h + r * 256 + sp * 32 + wsrc, myW + b * 2048 + q * 512 + lane * 8);
        async16(W1l + r * 256 + sp * 32 + wsrc, myW + b * 2048 + 1024 + q * 512 + lane * 8);
      }
    };
    auto stageW2 = [&](int tp) {
#pragma unroll
      for (int q = 0; q < 4; q++) {
        const long r = wn * 64 + q * 16 + wrow1;
        async16(W2h_ + r * 1024 + ch * 128 + tp * 32 + wsrc, myW + q * 512 + lane * 8);
        async16(W2l_ + r * 1024 + ch * 128 + tp * 32 + wsrc, myW + 2048 + q * 512 + lane * 8);
      }
    };

    stageW1(soff & 7, 0);
    f32x4 acc1[2][2];
#pragma unroll
    for (int i = 0; i < 2; i++)
#pragma unroll
      for (int j = 0; j < 2; j++) acc1[i][j] = f32x4{0.f, 0.f, 0.f, 0.f};

    for (int s = 0; s < 8; s++) {
      const int b = s & 1;
      const int sp = (s + soff) & 7;
      if (s < 7) {
        stageW1((s + 1 + soff) & 7, b ^ 1);
        asm volatile("s_waitcnt vmcnt(4)" ::: "memory");
      } else {
        asm volatile("s_waitcnt vmcnt(0)" ::: "memory");
      }
      bf16x8 a_h[2], a_l[2], w_h[2], w_l[2];
#pragma unroll
      for (int i = 0; i < 2; i++) {
        const int arow = i * 16 + l15;
        const int ac = (sp * 4 + lg) ^ (arow & 31);
        a_h[i] = *(const bf16x8*)&sAh[arow * 256 + ac * 8];
        a_l[i] = *(const bf16x8*)&sAl[arow * 256 + ac * 8];
      }
#pragma unroll
      for (int j = 0; j < 2; j++) {
        const int r = j * 16 + l15;
        w_h[j] = *(const bf16x8*)&myW[b * 2048 + r * 32 + rpc];
        w_l[j] = *(const bf16x8*)&myW[b * 2048 + 1024 + r * 32 + rpc];
      }
#pragma unroll
      for (int i = 0; i < 2; i++)
#pragma unroll
        for (int j = 0; j < 2; j++) {
          acc1[i][j] = __builtin_amdgcn_mfma_f32_16x16x32_bf16(w_h[j], a_h[i], acc1[i][j], 0, 0, 0);
          acc1[i][j] = __builtin_amdgcn_mfma_f32_16x16x32_bf16(w_h[j], a_l[i], acc1[i][j], 0, 0, 0);
          acc1[i][j] = __builtin_amdgcn_mfma_f32_16x16x32_bf16(w_l[j], a_h[i], acc1[i][j], 0, 0, 0);
        }
    }

    asm volatile("s_waitcnt lgkmcnt(0)" ::: "memory");
    stageW2(toff & 3);

#pragma unroll
    for (int i = 0; i < 2; i++) {
      const int m = i * 16 + l15;
      const int kb = (m0 + m) & 31;
#pragma unroll
      for (int j = 0; j < 2; j++) {
        const int u = wn * 4 + j * 2 + (lg >> 1);
        const int pu = u ^ (m & 7);
        const int base = m * 128 + pu * 8 + (lg & 1) * 4;
        const int ncol = wn * 32 + j * 16 + lg * 4;
        bf16x4 h4, l4;
#pragma unroll
        for (int rr = 0; rr < 4; rr++) {
          const float t = fast_tanh(acc1[i][j][rr] + b1[(ch * 128 + ncol + rr) * 32 + kb]);
          const bf16_t hh = (bf16_t)t;
          h4[rr] = hh;
          l4[rr] = (bf16_t)(t - (float)hh);
        }
        *(bf16x4*)&sHh[base] = h4;
        *(bf16x4*)&sHl[base] = l4;
      }
    }
    __syncthreads();

    for (int t = 0; t < 4; t++) {
      const int tp = (t + toff) & 3;
      asm volatile("s_waitcnt vmcnt(0)" ::: "memory");
      bf16x8 h_h[2], h_l[2], v_h[4], v_l[4];
#pragma unroll
      for (int i = 0; i < 2; i++) {
        const int hrow = i * 16 + l15;
        const int pu = (tp * 4 + lg) ^ (hrow & 7);
        h_h[i] = *(const bf16x8*)&sHh[hrow * 128 + pu * 8];
        h_l[i] = *(const bf16x8*)&sHl[hrow * 128 + pu * 8];
      }
#pragma unroll
      for (int j = 0; j < 4; j++) {
        const int r2 = j * 16 + l15;
        v_h[j] = *(const bf16x8*)&myW[r2 * 32 + rpc];
        v_l[j] = *(const bf16x8*)&myW[2048 + r2 * 32 + rpc];
      }
      if (t < 3) {
        asm volatile("s_waitcnt lgkmcnt(0)" ::: "memory");
        stageW2((t + 1 + toff) & 3);
      }
#pragma unroll
      for (int i = 0; i < 2; i++)
#pragma unroll
        for (int j = 0; j < 4; j++) {
          acc2[i][j] = __builtin_amdgcn_mfma_f32_16x16x32_bf16(h_h[i], v_h[j], acc2[i][j], 0, 0, 0);
          acc2[i][j] = __builtin_amdgcn_mfma_f32_16x16x32_bf16(h_h[i], v_l[j], acc2[i][j], 0, 0, 0);
          acc2[i][j] = __builtin_amdgcn_mfma_f32_16x16x32_bf16(h_l[i], v_h[j], acc2[i][j], 0, 0, 0);
        }
    }
    __syncthreads();
  }

#pragma unroll
  for (int i = 0; i < 2; i++)
#pragma unroll
    for (int j = 0; j < 4; j++) {
      const int n2 = wn * 64 + j * 16 + l15;
#pragma unroll
      for (int rr = 0; rr < 4; rr++) {
        const int m = m0 + i * 16 + lg * 4 + rr;
        XT[(long)m * 256 + n2] += acc2[i][j][rr] + b2[n2 * 32 + (m & 31)];
      }
    }
}

// dst[b][c][r] = src[b][r][c], 32x32 tiles (x -> XT only)
__global__ __launch_bounds__(256)
void transpose_k(const float* __restrict__ src, float* __restrict__ dst, int R, int C)
{
  __shared__ float t[32][33];
  const long boff = (long)blockIdx.z * R * C;
  const int r0 = blockIdx.y * 32, c0 = blockIdx.x * 32;
  const int tx = threadIdx.x & 31, ty = threadIdx.x >> 5;
#pragma unroll
  for (int i = 0; i < 32; i += 8)
    t[ty + i][tx] = src[boff + (long)(r0 + ty + i) * C + c0 + tx];
  __syncthreads();
#pragma unroll
  for (int i = 0; i < 32; i += 8)
    dst[boff + (long)(c0 + ty + i) * R + r0 + tx] = t[tx][ty + i];
}

DEV void hilo4(const f32x4 t, bf16x4& h, bf16x4& l) {
#pragma unroll
  for (int j = 0; j < 4; j++) {
    const bf16_t hh = (bf16_t)t[j];
    h[j] = hh;
    l[j] = (bf16_t)(t[j] - (float)hh);
  }
}

// Fused normalize_cl41 + layernorm2d, one WAVE per (b,s) row, no LDS/barriers.
// MODE bits: 1=norm over kb, 2=write normalized X, 4=layernorm->hi/lo, 8=emit hi/lo of v
template<int MODE>
__global__ __launch_bounds__(256)
void nl_k(const float* __restrict__ X, float* __restrict__ Xo,
          const float* __restrict__ wT, const float* __restrict__ bT,
          bf16_t* __restrict__ oh, bf16_t* __restrict__ ol)
{
  const int row = blockIdx.x * 4 + (threadIdx.x >> 6);
  const int l   = threadIdx.x & 63;
  const float4* Xr = (const float4*)X + (long)row * 2048 + l;
  f32x4 v[32];
#pragma unroll
  for (int kb = 0; kb < 32; kb++) {
    const float4 t = Xr[kb * 64];
    v[kb] = f32x4{t.x, t.y, t.z, t.w};
  }
  if constexpr (MODE & 1) {
    f32x4 ss = f32x4{1e-6f, 1e-6f, 1e-6f, 1e-6f};
#pragma unroll
    for (int kb = 0; kb < 32; kb++) ss += v[kb] * v[kb];
    const f32x4 rs = f32x4{rsqrtf(ss[0]), rsqrtf(ss[1]), rsqrtf(ss[2]), rsqrtf(ss[3])};
#pragma unroll
    for (int kb = 0; kb < 32; kb++) v[kb] *= rs;
    if constexpr (MODE & 2) {
      float4* Xw = (float4*)Xo + (long)row * 2048 + l;
#pragma unroll
      for (int kb = 0; kb < 32; kb++)
        Xw[kb * 64] = float4{v[kb][0], v[kb][1], v[kb][2], v[kb][3]};
    }
  }
  if constexpr (MODE & 4) {
    float s = 0.f, s2 = 0.f;
#pragma unroll
    for (int kb = 0; kb < 32; kb++) {
      s  += (v[kb][0] + v[kb][1]) + (v[kb][2] + v[kb][3]);
      s2 += (v[kb][0] * v[kb][0] + v[kb][1] * v[kb][1]) +
            (v[kb][2] * v[kb][2] + v[kb][3] * v[kb][3]);
    }
#pragma unroll
    for (int o = 32; o > 0; o >>= 1) { s += __shfl_xor(s, o); s2 += __shfl_xor(s2, o); }
    const float mean = s * (1.f / 8192.f);
    const float var  = s2 * (1.f / 8192.f) - mean * mean;
    const float rstd = rsqrtf(var + 1e-5f);
    const float4* w4 = (const float4*)wT + l;
    const float4* b4 = (const float4*)bT + l;
#pragma unroll
    for (int kb = 0; kb < 32; kb++) {
      const float4 ww = w4[kb * 64];
      const float4 bb = b4[kb * 64];
      f32x4 t;
      t[0] = (v[kb][0] - mean) * rstd * ww.x + bb.x;
      t[1] = (v[kb][1] - mean) * rstd * ww.y + bb.y;
      t[2] = (v[kb][2] - mean) * rstd * ww.z + bb.z;
      t[3] = (v[kb][3] - mean) * rstd * ww.w + bb.w;
      bf16x4 h4, l4;
      hilo4(t, h4, l4);
      const long oi = (long)row * 8192 + kb * 256 + l * 4;
      *(bf16x4*)&oh[oi] = h4;
      *(bf16x4*)&ol[oi] = l4;
    }
  }
  if constexpr (MODE & 8) {
#pragma unroll
    for (int kb = 0; kb < 32; kb++) {
      bf16x4 h4, l4;
      hilo4(v[kb], h4, l4);
      const long oi = (long)row * 8192 + kb * 256 + l * 4;
      *(bf16x4*)&oh[oi] = h4;
      *(bf16x4*)&ol[oi] = l4;
    }
  }
}

// softmax over rows of 512 (summing split-K2 halves), one wave per row; hi/lo bf16 out
__global__ __launch_bounds__(256)
void softmax_k(const float* __restrict__ SC, const float* __restrict__ SC2,
               bf16_t* __restrict__ Ph, bf16_t* __restrict__ Pl)
{
  const int row = blockIdx.x * 4 + (threadIdx.x >> 6);
  const int lane = threadIdx.x & 63;
  const float* s1 = SC  + (long)row * 512;
  const float* s2 = SC2 + (long)row * 512;
  float4 a = *(const float4*)&s1[lane * 4];
  float4 c = *(const float4*)&s1[256 + lane * 4];
  const float4 a2 = *(const float4*)&s2[lane * 4];
  const float4 c2 = *(const float4*)&s2[256 + lane * 4];
  a.x += a2.x; a.y += a2.y; a.z += a2.z; a.w += a2.w;
  c.x += c2.x; c.y += c2.y; c.z += c2.z; c.w += c2.w;
  float mx = fmaxf(fmaxf(fmaxf(a.x, a.y), fmaxf(a.z, a.w)),
                   fmaxf(fmaxf(c.x, c.y), fmaxf(c.z, c.w)));
#pragma unroll
  for (int o = 32; o > 0; o >>= 1) mx = fmaxf(mx, __shfl_xor(mx, o));
  float e[8] = {expf(a.x - mx), expf(a.y - mx), expf(a.z - mx), expf(a.w - mx),
                expf(c.x - mx), expf(c.y - mx), expf(c.z - mx), expf(c.w - mx)};
  float sum = ((e[0] + e[1]) + (e[2] + e[3])) + ((e[4] + e[5]) + (e[6] + e[7]));
#pragma unroll
  for (int o = 32; o > 0; o >>= 1) sum += __shfl_xor(sum, o);
  const float inv = 1.f / sum;
  bf16x4 h0, h1, l0, l1;
#pragma unroll
  for (int j = 0; j < 4; j++) {
    const float p0 = e[j] * inv, p1 = e[4 + j] * inv;
    h0[j] = (bf16_t)p0; l0[j] = (bf16_t)(p0 - (float)h0[j]);
    h1[j] = (bf16_t)p1; l1[j] = (bf16_t)(p1 - (float)h1[j]);
  }
  *(bf16x4*)&Ph[(long)row * 512 + lane * 4] = h0;
  *(bf16x4*)&Ph[(long)row * 512 + 256 + lane * 4] = h1;
  *(bf16x4*)&Pl[(long)row * 512 + lane * 4] = l0;
  *(bf16x4*)&Pl[(long)row * 512 + 256 + lane * 4] = l1;
}

// compile-time Cayley sign for Cl(4,1): gp(e_i, e_j) = sign * e_{i^j}
constexpr float gpsign(int i, int j) {
  int cnt = 0;
  for (int s = 1; s < 5; s++) cnt += __builtin_popcount((i >> s) & j);
  float sgn = (cnt & 1) ? -1.f : 1.f;
  if ((i & j) & 16) sgn = -sgn;   // metric e4^2 = -1
  return sgn;
}

// per-thread full geometric product, fully unrolled, constant signs (no shuffles)
DEV void gp32(const float* __restrict__ a, const float* __restrict__ b, float* __restrict__ o) {
#pragma unroll
  for (int k = 0; k < 32; k++) {
    float s0 = 0.f, s1 = 0.f;
#pragma unroll
    for (int i = 0; i < 32; i += 2) {
      s0 = fmaf(gpsign(i, i ^ k) * a[i], b[i ^ k], s0);
      s1 = fmaf(gpsign(i + 1, (i + 1) ^ k) * a[i + 1], b[(i + 1) ^ k], s1);
    }
    o[k] = s0 + s1;
  }
}

// Tree-structured rotor product: psi = normalize(r_511 o ... o r_0).
__global__ __launch_bounds__(256)
void gptree_k(const float* __restrict__ dT, float* __restrict__ psiO)
{
  __shared__ float bufA[256 * 33];
  __shared__ float bufB[128 * 33];
  const int chain = blockIdx.x;
  const int t = threadIdx.x;
  const float* src = dT + (long)chain * (512 * 32);
  {
    float v[64];
    const float4* g = (const float4*)(src + t * 64);
#pragma unroll
    for (int i = 0; i < 16; i++) *(float4*)&v[i * 4] = g[i];
    float o[32];
    gp32(v + 32, v, o);               // left = later timestep
    float ss = 1e-6f;
#pragma unroll
    for (int k = 0; k < 32; k++) ss = fmaf(o[k], o[k], ss);
    const float rs = rsqrtf(ss);
#pragma unroll
    for (int k = 0; k < 32; k++) bufA[t * 33 + k] = o[k] * rs;
  }
  __syncthreads();
  int cur = 0;
#pragma unroll 1
  for (int P = 128; P >= 1; P >>= 1) {
    const float* in = cur ? bufB : bufA;
    float* ob = cur ? bufA : bufB;
    if (t < P) {
      float a[32], b[32], o[32];
#pragma unroll
      for (int c = 0; c < 32; c++) { b[c] = in[t * 66 + c]; a[c] = in[t * 66 + 33 + c]; }
      gp32(a, b, o);
      float ss = 1e-6f;
#pragma unroll
      for (int k = 0; k < 32; k++) ss = fmaf(o[k], o[k], ss);
      const float rs = rsqrtf(ss);
#pragma unroll
      for (int k = 0; k < 32; k++) ob[t * 33 + k] = o[k] * rs;
    }
    cur ^= 1;
    __syncthreads();
  }
  if (t < 32) psiO[(long)chain * 32 + t] = (cur ? bufB : bufA)[t];
}

// logits[b, c] = psi[b,:] . wc[c,:] + bc[c]; one block per class
__global__ __launch_bounds__(256)
void cls_k(const float* __restrict__ psi, const float* __restrict__ wcw,
           const float* __restrict__ bc, float* __restrict__ out)
{
  const int c = blockIdx.x;
  const int tid = threadIdx.x;
  float a0 = 0.f, a1 = 0.f, a2 = 0.f, a3 = 0.f;
  for (int i = tid * 4; i < 8192; i += 1024) {
    const float4 w  = *(const float4*)&wcw[(long)c * 8192 + i];
    const float4 p0 = *(const float4*)&psi[i];
    const float4 p1 = *(const float4*)&psi[8192 + i];
    const float4 p2 = *(const float4*)&psi[16384 + i];
    const float4 p3 = *(const float4*)&psi[24576 + i];
    a0 += w.x * p0.x + w.y * p0.y + w.z * p0.z + w.w * p0.w;
    a1 += w.x * p1.x + w.y * p1.y + w.z * p1.z + w.w * p1.w;
    a2 += w.x * p2.x + w.y * p2.y + w.z * p2.z + w.w * p2.w;
    a3 += w.x * p3.x + w.y * p3.y + w.z * p3.z + w.w * p3.w;
  }
#pragma unroll
  for (int o = 32; o > 0; o >>= 1) {
    a0 += __shfl_down(a0, o); a1 += __shfl_down(a1, o);
    a2 += __shfl_down(a2, o); a3 += __shfl_down(a3, o);
  }
  __shared__ float red[4][4];
  const int wv = tid >> 6;
  if ((tid & 63) == 0) { red[wv][0] = a0; red[wv][1] = a1; red[wv][2] = a2; red[wv][3] = a3; }
  __syncthreads();
  if (tid < 4) {
    const float r = red[0][tid] + red[1][tid] + red[2][tid] + red[3][tid] + bc[c];
    out[(long)tid * 1000 + c] = r;
  }
}

// Merged weight-prep: z selects tensor; hi/lo split with grid-stride.
// z: 0=wq,1=wk,2=wv (interleaved into WQKV), 3=wo, 4=w1, 5=w2, 6=wr
__global__ __launch_bounds__(256)
void prepsplit_k(const float* __restrict__ wq, const float* __restrict__ wk,
                 const float* __restrict__ wv, const float* __restrict__ wo,
                 const float* __restrict__ w1, const float* __restrict__ w2,
                 const float* __restrict__ wr,
                 bf16_t* __restrict__ WQKVh, bf16_t* __restrict__ WQKVl,
                 bf16_t* __restrict__ WOh, bf16_t* __restrict__ WOl,
                 bf16_t* __restrict__ W1h, bf16_t* __restrict__ W1l,
                 bf16_t* __restrict__ W2h, bf16_t* __restrict__ W2l,
                 bf16_t* __restrict__ WRh, bf16_t* __restrict__ WRl)
{
  const int z = blockIdx.z;
  const float* src; bf16_t *dh, *dl; int n;
  switch (z) {
    case 0: src = wq; dh = WQKVh; dl = WQKVl; n = 131072; break;
    case 1: src = wk; dh = WQKVh; dl = WQKVl; n = 131072; break;
    case 2: src = wv; dh = WQKVh; dl = WQKVl; n = 131072; break;
    case 3: src = wo; dh = WOh;   dl = WOl;   n = 131072; break;
    case 4: src = w1; dh = W1h;   dl = W1l;   n = 524288; break;
    case 5: src = w2; dh = W2h;   dl = W2l;   n = 524288; break;
    default: src = wr; dh = WRh;  dl = WRl;   n = 65536;  break;
  }
  const bool qkv = (z < 3);
  for (int i = blockIdx.x * 256 + threadIdx.x; i < n; i += gridDim.x * 256) {
    const float v = src[i];
    const bf16_t hh = (bf16_t)v;
    const long o = qkv ? ((long)(i >> 16) * 196608 + z * 65536 + (i & 65535)) : (long)i;
    dh[o] = hh;
    dl[o] = (bf16_t)(v - (float)hh);
  }
}

// Merged misc prep: z 0..2 = bias copies into BQKV; z 3..6 = LN (L,D,K)->(L,K,D)
__global__ __launch_bounds__(256)
void prepmisc_k(const float* __restrict__ bq, const float* __restrict__ bk,
                const float* __restrict__ bv, float* __restrict__ BQKV,
                const float* __restrict__ ln1w, const float* __restrict__ ln1b,
                const float* __restrict__ ln2w, const float* __restrict__ ln2b,
                float* __restrict__ LNT)
{
  const int z = blockIdx.z;
  const int i = blockIdx.x * 256 + threadIdx.x;   // 0..16383
  if (z < 3) {
    const float* s = (z == 0) ? bq : (z == 1) ? bk : bv;
    const int l = i >> 13, w = i & 8191;
    BQKV[l * 24576 + z * 8192 + w] = s[i];
  } else {
    const float* s = (z == 3) ? ln1w : (z == 4) ? ln1b : (z == 5) ? ln2w : ln2b;
    float* d = LNT + (long)(z - 3) * 16384;
    const int l = i >> 13, r = i & 8191;
    const int kb = r >> 8, dd = r & 255;
    d[i] = s[l * 8192 + dd * 32 + kb];
  }
}

extern "C" void kernel_launch(void* const* d_in, const int* in_sizes, int n_in,
                              void* d_out, int out_size, void* d_ws, size_t ws_size,
                              hipStream_t stream)
{
  const float* x    = (const float*)d_in[0];
  const float* ln1w = (const float*)d_in[1];
  const float* ln1b = (const float*)d_in[2];
  const float* wq   = (const float*)d_in[3];
  const float* bq   = (const float*)d_in[4];
  const float* wk   = (const float*)d_in[5];
  const float* bk   = (const float*)d_in[6];
  const float* wvv  = (const float*)d_in[7];
  const float* bv   = (const float*)d_in[8];
  const float* wo   = (const float*)d_in[9];
  const float* bo   = (const float*)d_in[10];
  const float* ln2w = (const float*)d_in[11];
  const float* ln2b = (const float*)d_in[12];
  const float* w1   = (const float*)d_in[13];
  const float* b1   = (const float*)d_in[14];
  const float* w2   = (const float*)d_in[15];
  const float* b2   = (const float*)d_in[16];
  const float* wr   = (const float*)d_in[17];
  const float* br   = (const float*)d_in[18];
  const float* wcw  = (const float*)d_in[19];
  const float* bc   = (const float*)d_in[20];
  float* out = (float*)d_out;

  char* ws = (char*)d_ws;
  const size_t MB = 1ull << 20;
  const size_t KB = 1024;
  // Overlay map (peak ~200.4MB):
  float*  XT   = (float*)(ws + 0);             // 0-64    fp32 residual (b,s,kb,d)
  bf16_t* HBh  = (bf16_t*)(ws + 64 * MB);      // 64-96   ln out hi
  bf16_t* HBl  = (bf16_t*)(ws + 96 * MB);      // 96-128  ln out lo
  bf16_t* QKVh = (bf16_t*)(ws + 128 * MB);     // 128-152 (24MB: Q|K|V hi)
  bf16_t* QKVl = (bf16_t*)(ws + 152 * MB);     // 152-176 (24MB: Q|K|V lo)
  float*  SCb  = (float*)(ws + 176 * MB);      // 176-184 fp32 scores half0 (h,q,s)
  float*  SC2b = (float*)(ws + 184 * MB);      // 184-192 fp32 scores half1
  bf16_t* Ph   = QKVh;
  bf16_t* Pl   = QKVl;
  bf16_t* OBh  = QKVh + 4194304;
  bf16_t* OBl  = QKVl + 4194304;
  bf16_t* Vh   = QKVh + 8388608;
  bf16_t* Vl   = QKVl + 8388608;
  bf16_t* XHI = (bf16_t*)(ws + 64 * MB), *XLO = (bf16_t*)(ws + 96 * MB);
  float*  DELTAT = (float*)(ws + 128 * MB);    // 128-192 (b,d,t,kb)
  float*  PSI  = (float*)(ws + 192 * MB);      // 128KB
  char*   W    = ws + 193 * MB;
  bf16_t* WQKVh = (bf16_t*)(W);                // 2 layers x 768x256 (768KB)
  bf16_t* WQKVl = (bf16_t*)(W + 1 * MB);
  bf16_t* W1h = (bf16_t*)(W + 2 * MB);   bf16_t* W1l = (bf16_t*)(W + 3 * MB);
  bf16_t* W2h = (bf16_t*)(W + 4 * MB);   bf16_t* W2l = (bf16_t*)(W + 5 * MB);
  bf16_t* WOh = (bf16_t*)(W + 6 * MB);   bf16_t* WOl = (bf16_t*)(W + 6 * MB + 256 * KB);
  bf16_t* WRh = (bf16_t*)(W + 6 * MB + 512 * KB);
  bf16_t* WRl = (bf16_t*)(W + 6 * MB + 640 * KB);
  float*  BQKV = (float*)(W + 6 * MB + 768 * KB);  // 2 layers x 768x32 fp32 (192KB)
  float*  LNT  = (float*)(W + 6 * MB + 960 * KB);  // 4 tensors x 2 layers x 8192 fp32 (256KB)
  float* LN1WT = LNT, *LN1BT = LNT + 16384, *LN2WT = LNT + 32768, *LN2BT = LNT + 49152;

  // merged weight prep (2 launches instead of 22)
  prepsplit_k<<<dim3(512, 1, 7), 256, 0, stream>>>(
      wq, wk, wvv, wo, w1, w2, wr,
      WQKVh, WQKVl, WOh, WOl, W1h, W1l, W2h, W2l, WRh, WRl);
  prepmisc_k<<<dim3(64, 1, 7), 256, 0, stream>>>(
      bq, bk, bv, BQKV, ln1w, ln1b, ln2w, ln2b, LNT);

  // x (B,S,D,K) -> XT (B,S,K,D)
  transpose_k<<<dim3(1, 8, 2048), 256, 0, stream>>>(x, XT, 256, 32);

  for (int l = 0; l < 2; l++) {
    if (l == 0)
      nl_k<4><<<512, 256, 0, stream>>>(XT, nullptr, LN1WT, LN1BT, HBh, HBl);
    for (int b = 0; b < 4; b++) {
      const long ao = (long)b * 16384 * 256;
      gemm_k<EPI_QKV, false><<<dim3(6, 128, 1), 256, 0, stream>>>(
          HBh + ao, HBl + ao, WQKVh + l * 196608, WQKVl + l * 196608,
          BQKV + l * 24576, QKVh, QKVl, 256, 256, 256, 0, 0);
      gemm_k<EPI_SCORE, false><<<dim3(4, 4, 16), 256, 0, stream>>>(
          QKVh, QKVl, QKVh + 4194304, QKVl + 4194304,
          nullptr, SCb, SC2b, 512, 1024, 1024, 512 * 1024, 512 * 1024);
      softmax_k<<<1024, 256, 0, stream>>>(SCb, SC2b, Ph, Pl);
      gemm_k<EPI_PV, true><<<dim3(8, 4, 8), 256, 0, stream>>>(
          Ph, Pl, Vh, Vl, nullptr, OBh, OBl, 512, 512, 1024, 512 * 512, 512 * 1024);
      gemm_k<EPI_RESID, false><<<dim3(2, 128, 1), 256, 0, stream>>>(
          OBh, OBl, WOh + l * 65536, WOl + l * 65536,
          bo + l * 8192, (float*)XT + ao, nullptr, 256, 256, 256, 0, 0);
    }
    // fused: normalize + ln2 -> HB hi/lo
    nl_k<1 | 2 | 4><<<512, 256, 0, stream>>>(XT, XT, LN2WT + l * 8192, LN2BT + l * 8192, HBh, HBl);
    // fused FFN v4 (per-wave W staging, full 3-MFMA split, 2 blocks/CU)
    ffn_k<<<2048, 256, 0, stream>>>(HBh, HBl,
                                    W1h + l * 262144, W1l + l * 262144,
                                    W2h + l * 262144, W2l + l * 262144,
                                    b1 + l * 32768, b2 + l * 8192, XT);
    if (l == 0) {
      nl_k<1 | 2 | 4><<<512, 256, 0, stream>>>(XT, XT, LN1WT + 8192, LN1BT + 8192, HBh, HBl);
    } else {
      nl_k<1 | 8><<<512, 256, 0, stream>>>(XT, nullptr, nullptr, nullptr, XHI, XLO);
    }
  }

  // delta = vlinear(x, wr, br), fp32-grade; epilogue writes (b,d,t,kb) directly
  gemm_k<EPI_DELTAT, false><<<dim3(2, 512, 1), 256, 0, stream>>>(
      XHI, XLO, WRh, WRl, br, DELTAT, nullptr, 256, 256, 256, 0, 0);
  gptree_k<<<1024, 256, 0, stream>>>(DELTAT, PSI);
  cls_k<<<1000, 256, 0, stream>>>(PSI, wcw, bc, out);
}